// Round 5
// baseline (9587.266 us; speedup 1.0000x reference)
//
#include <hip/hip_runtime.h>

// Problem dims (fixed)
constexpr int BATCH = 64;
constexpr int SEQ   = 512;
constexpr int DIN   = 512;
constexpr int HID   = 512;
constexpr int LAY   = 2;
constexpr int G3    = 3 * HID;   // 1536
constexpr int WCOL  = 32;        // hidden cols per WG (16 WGs per cell)
constexpr int KPAD  = 520;       // row stride u16: 1040B = 16B-aligned, 2-way-free banks
constexpr int SLOTS = SEQ + 1;   // out0 ring: slot 0 = init h, slot t+1 = h after step t

typedef __attribute__((ext_vector_type(8))) short bf16x8;  // MFMA A/B frag (4 VGPRs)
typedef __attribute__((ext_vector_type(4))) float f32x4;   // MFMA C/D frag
typedef unsigned short u16;
typedef unsigned int   u32;
typedef unsigned long long u64;

__device__ __forceinline__ u16 f2bf(float f) {
  union { float f; u32 u; } v; v.f = f;
  return (u16)((v.u + 0x7fffu + ((v.u >> 16) & 1u)) >> 16);  // RNE
}

// ---- agent-scope (MALL / LLC) ops: cross-XCD path, as proven R0-R4 ----
__device__ __forceinline__ u64 ld_agent_u64(const u16* p) {
  return __hip_atomic_load((const u64*)p, __ATOMIC_RELAXED, __HIP_MEMORY_SCOPE_AGENT);
}
__device__ __forceinline__ bf16x8 ld_frag_agent(const u16* p) {
  union { u64 q[2]; bf16x8 f; } u;
  u.q[0] = ld_agent_u64(p);
  u.q[1] = ld_agent_u64(p + 4);
  return u.f;
}
__device__ __forceinline__ void st_agent_u16(u16* p, u16 v) {
  __hip_atomic_store(p, v, __ATOMIC_RELAXED, __HIP_MEMORY_SCOPE_AGENT);
}
__device__ __forceinline__ void st_agent_u32(u32* p, u32 v) {
  __hip_atomic_store(p, v, __ATOMIC_RELAXED, __HIP_MEMORY_SCOPE_AGENT);
}

// ---- XCD-local fast path ----
// Correctness argument: (1) vector L1 is WRITE-THROUGH (the ISA has no
// L1-writeback op, only invalidate -> plain stores always reach the XCD L2;
// vmcnt(0) at __syncthreads acks them at L2). (2) Producer's plain flag store
// issues after that barrier -> payload is in L2 before flag. (3) Consumer
// loads with sc0 (L1 bypass) read the same, single, coherent XCD L2. Used
// ONLY when the runtime XCC_ID rendezvous proves all 16 WGs share an XCD.
__device__ __forceinline__ u32 min16(u32 v) {
  #pragma unroll
  for (int off = 8; off >= 1; off >>= 1) {
    u32 o = (u32)__shfl_xor((int)v, off, 64);
    v = v < o ? v : o;
  }
  return v;
}
__device__ __forceinline__ void poll16_agent(const u32* f, u32 tgt) {
  const int idx = threadIdx.x & 15;
  for (;;) {
    u32 v = __hip_atomic_load(f + idx, __ATOMIC_RELAXED, __HIP_MEMORY_SCOPE_AGENT);
    if (min16(v) >= tgt) break;
    __builtin_amdgcn_s_sleep(1);
  }
  __asm__ volatile("" ::: "memory");
}
__device__ __forceinline__ void poll16_sc0(const u32* f, u32 tgt) {
  const u32* p = f + (threadIdx.x & 15);
  for (;;) {
    u32 v;
    asm volatile("global_load_dword %0, %1, off sc0\n\ts_waitcnt vmcnt(0)"
                 : "=v"(v) : "v"(p) : "memory");
    if (min16(v) >= tgt) break;
    __builtin_amdgcn_s_sleep(1);
  }
  __asm__ volatile("" ::: "memory");
}

struct Params {
  const float* input;     // [BATCH][SEQ][DIN]
  const float* enc_h;     // [LAY][BATCH][2*HID]
  const float* Wih[2];    // dir f/b: [LAY][G3][DIN]
  const float* Whh[2];    // [LAY][G3][HID]
  const float* bih[2];    // [LAY][G3]
  const float* bhh[2];    // [LAY][G3]
  float* out;             // [BATCH][SEQ][2H] ++ [LAY][BATCH][2H]
  u16* xin;               // [BATCH][SEQ][DIN] bf16
  u16* wih;               // [2dir][LAY][G3][DIN] bf16
  u16* whh;               // [2dir][LAY][G3][HID] bf16
  u16* out0;              // [2dir][SLOTS][BATCH][HID] bf16 L0 h ring (sc1, single-write)
  u16* hbf;               // [4 cells][2 parity][BATCH][HID] bf16 h broadcast
  u32* flags;             // u32[4096]: [cell*64]=own, [1024+dir*64]=dep, [2048+cell*64]=xcc
};

__global__ __launch_bounds__(256) void convert_kernel(Params p) {
  const int gtid = blockIdx.x * 256 + threadIdx.x;
  const int nthr = gridDim.x * 256;
  for (int i = gtid; i < BATCH * SEQ * DIN; i += nthr) p.xin[i] = f2bf(p.input[i]);
  for (int d = 0; d < 2; ++d) {
    const float* s1 = p.Wih[d];
    u16* d1 = p.wih + (size_t)d * LAY * G3 * DIN;
    for (int i = gtid; i < LAY * G3 * DIN; i += nthr) d1[i] = f2bf(s1[i]);
    const float* s2 = p.Whh[d];
    u16* d2 = p.whh + (size_t)d * LAY * G3 * HID;
    for (int i = gtid; i < LAY * G3 * HID; i += nthr) d2[i] = f2bf(s2[i]);
  }
  if (gtid < 4096) p.flags[gtid] = 0;
}

// 128 WGs launched; class = bid&7. Classes 0-3 are the 4 cells (layer*2+dir),
// 16 WGs each at bids {c, c+8, ..., c+120} -> same XCD under round-robin
// dispatch (verified at runtime; else MALL fallback). Classes 4-7 exit.
// Each WG: 32 hidden cols, 4 waves = 4 batch m-tiles. Per step: h-GEMM
// (A = h broadcast, B = LDS Whh slice) -> epilogue -> barrier -> flag ->
// x-GEMM(t+1) in the signal shadow (plain cached loads) -> own poll.
__global__ __launch_bounds__(256, 1) void recur_all(Params p) {
  const int cls = blockIdx.x & 7;
  if (cls >= 4) return;
  const int cell  = cls;
  const int layer = cell >> 1;
  const int dir   = cell & 1;
  const int slice = blockIdx.x >> 3;    // 0..15
  const int j0    = slice * WCOL;
  const int wave  = threadIdx.x >> 6;
  const int lane  = threadIdx.x & 63;
  const int lq = lane >> 4, ln = lane & 15;
  const int am = wave * 16 + ln;        // A-frag row (batch index)

  __shared__ u16 lwhh[3][WCOL][KPAD];   // 99,840 B
  __shared__ int s_local;

  // ---- stage Whh slice into LDS: rows [g][rr] 16B-aligned ----
  {
    const u16* whh = p.whh + ((size_t)dir * LAY + layer) * G3 * HID;
    for (int idx = threadIdx.x; idx < 3 * WCOL * 64; idx += 256) {
      const int k8 = idx & 63, row = idx >> 6;     // row = g*32 + rr
      const int g = row >> 5, rr = row & 31;
      *(bf16x8*)&lwhh[g][rr][k8 * 8] =
          *(const bf16x8*)(whh + (size_t)(g * HID + j0 + rr) * HID + k8 * 8);
    }
  }

  // ---- rendezvous: are all 16 WGs of this cell on one XCD? ----
  {
    const u32 xcc = (u32)__builtin_amdgcn_s_getreg(63508);  // hwreg(HW_REG_XCC_ID=20,0,32)
    u32* xarr = p.flags + 2048 + (size_t)cell * 64;
    if (threadIdx.x == 0) {
      st_agent_u32(xarr + slice, xcc + 1);
      for (;;) {
        bool all = true, uni = true; u32 r0 = 0;
        for (int i = 0; i < 16; ++i) {
          u32 v = __hip_atomic_load(xarr + i, __ATOMIC_RELAXED, __HIP_MEMORY_SCOPE_AGENT);
          if (i == 0) r0 = v;
          all = all && (v != 0);
          uni = uni && (v == r0);
        }
        if (all) { s_local = uni ? 1 : 0; break; }
        __builtin_amdgcn_s_sleep(8);
      }
    }
    __syncthreads();   // also covers LDS staging
  }
  const bool local = (s_local != 0);

  u16* o0 = p.out0 + (size_t)dir * SLOTS * BATCH * HID;
  u16* hbp[2] = { p.hbf + ((size_t)cell * 2 + 0) * BATCH * HID,
                  p.hbf + ((size_t)cell * 2 + 1) * BATCH * HID };
  u32* fown = p.flags + (size_t)cell * 64;
  u32* fdep = p.flags + 1024 + (size_t)dir * 64;

  const u16* wih = p.wih + ((size_t)dir * LAY + layer) * G3 * DIN;
  const u16* bri[3][2];
  #pragma unroll
  for (int g = 0; g < 3; ++g)
    #pragma unroll
    for (int s = 0; s < 2; ++s)
      bri[g][s] = wih + (size_t)(g * HID + j0 + s * 16 + ln) * DIN;

  const float* bih = p.bih[dir] + (size_t)layer * G3;
  const float* bhh = p.bhh[dir] + (size_t)layer * G3;
  float b_r[2], b_z[2], bi_n[2], bh_n[2];
  #pragma unroll
  for (int s = 0; s < 2; ++s) {
    const int jc = j0 + s * 16 + ln;
    b_r[s]  = bih[jc] + bhh[jc];
    b_z[s]  = bih[HID + jc] + bhh[HID + jc];
    bi_n[s] = bih[2 * HID + jc];
    bh_n[s] = bhh[2 * HID + jc];
  }

  // ---- init h (fp32 master) + broadcast ----
  float hreg[2][4];
  #pragma unroll
  for (int s = 0; s < 2; ++s)
    #pragma unroll
    for (int i = 0; i < 4; ++i) {
      const int m = wave * 16 + lq * 4 + i;       // C/D row = (lane>>4)*4 + reg
      const int jc = j0 + s * 16 + ln;
      hreg[s][i] = p.enc_h[((size_t)layer * BATCH + m) * (2 * HID) + (size_t)dir * HID + jc];
      const u16 h16 = f2bf(hreg[s][i]);
      const size_t off = (size_t)m * HID + jc;
      if (local) hbp[0][off] = h16;
      else if (layer == 1) st_agent_u16(&hbp[0][off], h16);
      if (layer == 0) st_agent_u16(&o0[off], h16);   // ring slot 0
    }

  __threadfence_block();
  __syncthreads();     // drains vmcnt(0): payload in L2 / MALL before flag
  if (threadIdx.x == 0) {
    if (local) { fown[slice] = 1; __asm__ volatile("" ::: "memory"); }
    else st_agent_u32(&fown[slice], 1);
    if (layer == 0) st_agent_u32(&fdep[slice], 1);
  }

  float* hsec = p.out + (size_t)BATCH * SEQ * 2 * HID;

  // ---- x-GEMM for step 0 ----
  f32x4 accx[3][2];
  #pragma unroll
  for (int g = 0; g < 3; ++g) { accx[g][0] = f32x4{0,0,0,0}; accx[g][1] = accx[g][0]; }
  if (layer == 1) poll16_agent(fdep, 2);   // ring slot 1 written
  {
    const u16* ax = (layer == 0)
        ? p.xin + ((size_t)am * SEQ + (dir ? SEQ - 1 : 0)) * DIN
        : o0 + (size_t)1 * BATCH * HID + (size_t)am * HID;
    #pragma unroll 4
    for (int k0 = 0; k0 < 512; k0 += 32) {
      const int koff = k0 + lq * 8;
      const bf16x8 a_x = *(const bf16x8*)(ax + koff);
      #pragma unroll
      for (int g = 0; g < 3; ++g)
        #pragma unroll
        for (int s = 0; s < 2; ++s)
          accx[g][s] = __builtin_amdgcn_mfma_f32_16x16x32_bf16(
              a_x, *(const bf16x8*)(bri[g][s] + koff), accx[g][s], 0, 0, 0);
    }
  }
  if (local) poll16_sc0(fown, 1); else poll16_agent(fown, 1);

  for (int t = 0; t < SEQ; ++t) {
    // ---- h-frag loads ----
    bf16x8 fh[16];
    const u16* hsrc = (local || layer == 1)
        ? hbp[t & 1] + (size_t)am * HID
        : o0 + (size_t)t * BATCH * HID + (size_t)am * HID;  // fallback L0: plain ring
    if (local) {
      #pragma unroll
      for (int kk = 0; kk < 16; ++kk)
        asm volatile("global_load_dwordx4 %0, %1, off sc0"
                     : "=v"(fh[kk]) : "v"(hsrc + kk * 32 + lq * 8));
      asm volatile("s_waitcnt vmcnt(0)" ::: "memory");
      __builtin_amdgcn_sched_barrier(0);
    } else if (layer == 0) {
      #pragma unroll
      for (int kk = 0; kk < 16; ++kk) fh[kk] = *(const bf16x8*)(hsrc + kk * 32 + lq * 8);
    } else {
      #pragma unroll
      for (int kk = 0; kk < 16; ++kk) fh[kk] = ld_frag_agent(hsrc + kk * 32 + lq * 8);
    }

    // ---- h-GEMM: B from aligned LDS ----
    f32x4 acch[3][2];
    #pragma unroll
    for (int g = 0; g < 3; ++g) { acch[g][0] = f32x4{0,0,0,0}; acch[g][1] = acch[g][0]; }
    #pragma unroll
    for (int kk = 0; kk < 16; ++kk) {
      const int koff = kk * 32 + lq * 8;
      #pragma unroll
      for (int g = 0; g < 3; ++g)
        #pragma unroll
        for (int s = 0; s < 2; ++s)
          acch[g][s] = __builtin_amdgcn_mfma_f32_16x16x32_bf16(
              fh[kk], *(const bf16x8*)&lwhh[g][s * 16 + ln][koff], acch[g][s], 0, 0, 0);
    }

    // ---- gate epilogue + stores ----
    u16* hw = hbp[(t + 1) & 1];
    u16* ow = o0 + (size_t)(t + 1) * BATCH * HID;
    const int tt = dir ? (SEQ - 1 - t) : t;
    #pragma unroll
    for (int s = 0; s < 2; ++s)
      #pragma unroll
      for (int i = 0; i < 4; ++i) {
        const int m = wave * 16 + lq * 4 + i;
        const int jc = j0 + s * 16 + ln;
        const float r = 1.f / (1.f + __expf(-(accx[0][s][i] + acch[0][s][i] + b_r[s])));
        const float z = 1.f / (1.f + __expf(-(accx[1][s][i] + acch[1][s][i] + b_z[s])));
        const float n = tanhf(accx[2][s][i] + bi_n[s] + r * (acch[2][s][i] + bh_n[s]));
        const float hnew = (1.f - z) * n + z * hreg[s][i];
        hreg[s][i] = hnew;
        const u16 h16 = f2bf(hnew);
        const size_t off = (size_t)m * HID + jc;
        if (t + 1 < SEQ) {
          if (local) hw[off] = h16;
          else if (layer == 1) st_agent_u16(&hw[off], h16);
        }
        if (layer == 0) st_agent_u16(&ow[off], h16);
        else p.out[((size_t)m * SEQ + tt) * (2 * HID) + (size_t)dir * HID + jc] = hnew;
        if (t == SEQ - 1)
          hsec[((size_t)layer * BATCH + m) * (2 * HID) + (size_t)dir * HID + jc] = hnew;
      }

    // ---- signal ----
    __threadfence_block();
    __syncthreads();     // vmcnt(0): all payload stores acked before flag
    if (threadIdx.x == 0) {
      if (local) { fown[slice] = (u32)(t + 2); __asm__ volatile("" ::: "memory"); }
      else st_agent_u32(&fown[slice], (u32)(t + 2));
      if (layer == 0) st_agent_u32(&fdep[slice], (u32)(t + 2));
    }

    if (t + 1 < SEQ) {
      // ---- x-GEMM for t+1 in the signal shadow (plain cached loads) ----
      if (layer == 1) poll16_agent(fdep, (u32)(t + 3));   // ring slot t+2 written
      const int tn = t + 1;
      const u16* ax = (layer == 0)
          ? p.xin + ((size_t)am * SEQ + (dir ? SEQ - 1 - tn : tn)) * DIN
          : o0 + (size_t)(tn + 1) * BATCH * HID + (size_t)am * HID;
      #pragma unroll
      for (int g = 0; g < 3; ++g) { accx[g][0] = f32x4{0,0,0,0}; accx[g][1] = accx[g][0]; }
      #pragma unroll 4
      for (int k0 = 0; k0 < 512; k0 += 32) {
        const int koff = k0 + lq * 8;
        const bf16x8 a_x = *(const bf16x8*)(ax + koff);
        #pragma unroll
        for (int g = 0; g < 3; ++g)
          #pragma unroll
          for (int s = 0; s < 2; ++s)
            accx[g][s] = __builtin_amdgcn_mfma_f32_16x16x32_bf16(
                a_x, *(const bf16x8*)(bri[g][s] + koff), accx[g][s], 0, 0, 0);
      }
      if (local) poll16_sc0(fown, (u32)(t + 2)); else poll16_agent(fown, (u32)(t + 2));
    }
  }
}

extern "C" void kernel_launch(void* const* d_in, const int* in_sizes, int n_in,
                              void* d_out, int out_size, void* d_ws, size_t ws_size,
                              hipStream_t stream) {
  Params p;
  p.input  = (const float*)d_in[0];
  p.enc_h  = (const float*)d_in[1];
  p.Wih[0] = (const float*)d_in[2];
  p.Whh[0] = (const float*)d_in[3];
  p.bih[0] = (const float*)d_in[4];
  p.bhh[0] = (const float*)d_in[5];
  p.Wih[1] = (const float*)d_in[6];
  p.Whh[1] = (const float*)d_in[7];
  p.bih[1] = (const float*)d_in[8];
  p.bhh[1] = (const float*)d_in[9];
  p.out = (float*)d_out;

  uintptr_t base = (uintptr_t)d_ws;
  size_t off = 0;
  auto take = [&](size_t bytes) -> void* {
    void* r = (void*)(base + off);
    off += (bytes + 255) & ~(size_t)255;
    return r;
  };
  p.xin   = (u16*)take((size_t)BATCH * SEQ * DIN * 2);         // 33.6 MB
  p.wih   = (u16*)take((size_t)2 * LAY * G3 * DIN * 2);        //  6.3 MB
  p.whh   = (u16*)take((size_t)2 * LAY * G3 * HID * 2);        //  6.3 MB
  p.out0  = (u16*)take((size_t)2 * SLOTS * BATCH * HID * 2);   // 67.2 MB
  p.hbf   = (u16*)take((size_t)4 * 2 * BATCH * HID * 2);       //  1.0 MB
  p.flags = (u32*)take((size_t)4096 * 4);                      //   16 KB
  if (off > ws_size) return;  // ~114 MB required (same budget as before)

  convert_kernel<<<dim3(2048), dim3(256), 0, stream>>>(p);
  recur_all<<<dim3(128), dim3(256), 0, stream>>>(p);
}